// Round 13
// baseline (34.071 us; speedup 1.0000x reference)
//
#include <hip/hip_runtime.h>
#include <math.h>

#define BB_ 512
#define NN_ 128
#define DD_ 64
#define NE_ 6
#define NB_ 4

// f32 workspace region (float offsets)
#define WS_PAIRE 0    // 144
#define WS_AE    144  // 6
#define WS_ENT   152  // 6
// ushort region at float offset 256:
//   [0, 768*256)        stability bf16 table, row (n*6+t)*256 + o
//   [TDOFF_, +768*256)  druglikeness bf16 table
//   [W2OFF_ + which*32768 + k*256 + o] W2 TRANSPOSED bf16
#define U16BASE_ 256
#define TDOFF_   (768 * 256)
#define W2OFF_   (1536 * 256)

typedef unsigned short u16x8 __attribute__((ext_vector_type(8)));

__device__ __forceinline__ ushort f2b(float f) {
  unsigned u = __float_as_uint(f);
  u += 0x7FFFu + ((u >> 16) & 1u);
  return (ushort)(u >> 16);
}
__device__ __forceinline__ float b2f(ushort h) {
  return __uint_as_float(((unsigned)h) << 16);
}

// ---------------------------------------------------------------------------
__device__ __forceinline__ float block_reduce256(float v, volatile float* red4,
                                                 int tid) {
#pragma unroll
  for (int off = 32; off > 0; off >>= 1) v += __shfl_down(v, off);
  __syncthreads();
  if ((tid & 63) == 0) red4[tid >> 6] = v;
  __syncthreads();
  return red4[0] + red4[1] + red4[2] + red4[3];
}

// ---------------------------------------------------------------------------
// k_pre: blk 0..1023  -> bf16 layer1 tables (n=blk>>3, which, oquad)
//        blk 1024     -> zero out[0..1024)
//        blk 1025..1168 -> pairE entries
//        blk 1169     -> ae/ent tables
//        blk 1170..1185 -> W2 transposed bf16 conversion
// ---------------------------------------------------------------------------
__global__ __launch_bounds__(256, 4) void k_pre(
    const float* __restrict__ emb, const float* __restrict__ ae_w,
    const float* __restrict__ ae_b, const float* __restrict__ ent_w,
    const float* __restrict__ ent_b, const float* __restrict__ bW,
    const float* __restrict__ sW1, const float* __restrict__ dW1,
    const float* __restrict__ sW2, const float* __restrict__ dW2,
    float* __restrict__ ws, float* __restrict__ out) {
  int blk = blockIdx.x;
  int tid = threadIdx.x;
  ushort* U = (ushort*)(ws + U16BASE_);

  if (blk < 1024) {
    // table build: n (128) x which (2) x oquad (4); thread = (dquad, o_local)
    int n = blk >> 3;
    int sub = blk & 7;
    int which = sub >> 2;
    int oquad = sub & 3;
    const float* W1 = which ? dW1 : sW1;
    ushort* T = U + (which ? TDOFF_ : 0);
    __shared__ float e_s[NE_ * DD_];
    __shared__ float part[4][NE_][64];
    for (int i = tid; i < NE_ * DD_; i += 256) e_s[i] = emb[i];
    __syncthreads();
    int dquad = tid >> 6;
    int o_local = tid & 63;
    int o = oquad * 64 + o_local;
    float acc[NE_] = {0.f, 0.f, 0.f, 0.f, 0.f, 0.f};
    const float* Wp = W1 + ((size_t)(n * DD_ + dquad * 16)) * 256 + o;
#pragma unroll
    for (int d = 0; d < 16; ++d) {
      float w = Wp[(size_t)d * 256];
#pragma unroll
      for (int t = 0; t < NE_; ++t) acc[t] += e_s[t * DD_ + dquad * 16 + d] * w;
    }
#pragma unroll
    for (int t = 0; t < NE_; ++t) part[dquad][t][o_local] = acc[t];
    __syncthreads();
    if (tid < NE_ * 64) {
      int t = tid >> 6;
      int ol = tid & 63;
      float s = part[0][t][ol] + part[1][t][ol] + part[2][t][ol] +
                part[3][t][ol];
      T[(n * NE_ + t) * 256 + oquad * 64 + ol] = f2b(s);
    }
  } else if (blk == 1024) {
    float4 z = make_float4(0.f, 0.f, 0.f, 0.f);
    ((float4*)out)[tid] = z;  // out[0..1024): energy+entropy accumulators
  } else if (blk < 1169) {
    int e = blk - 1025;
    int k = e / 36;
    int rem = e - k * 36;
    int ti = rem / 6, tj = rem - (rem / 6) * 6;
    int d = tid & 63;
    int qd = tid >> 6;
    const float* Wrow = bW + ((size_t)k * DD_ + d) * DD_ + qd * 16;
    const float* xj = emb + tj * DD_ + qd * 16;
    float a = 0.f;
#pragma unroll
    for (int u = 0; u < 16; ++u) a += Wrow[u] * xj[u];
    float c = emb[ti * DD_ + d] * a;
    __shared__ float red4[4];
    c = block_reduce256(c, red4, tid);
    if (tid == 0) ws[WS_PAIRE + e] = c;
  } else if (blk == 1169) {
    int g = tid >> 6, lane = tid & 63;
    for (int idx = g; idx < 12; idx += 4) {
      int t = idx - (idx >= 6 ? 6 : 0);
      bool ent = idx >= 6;
      float c = emb[t * DD_ + lane] * (ent ? ent_w[lane] : ae_w[lane]);
#pragma unroll
      for (int off = 32; off > 0; off >>= 1) c += __shfl_down(c, off);
      if (lane == 0)
        ws[(ent ? WS_ENT : WS_AE) + t] = c + (ent ? ent_b[0] : ae_b[0]);
    }
  } else {
    // W2 TRANSPOSED bf16 conversion: dst[head][k][o] = src[o*128+k]
    int base = (blk - 1170) * 4096 + tid;
#pragma unroll
    for (int u = 0; u < 16; ++u) {
      int e = base + u * 256;
      int head = e >> 15;
      int idx = e & 32767;  // k*256 + o
      int k = idx >> 8;
      int o = idx & 255;
      const float* src = head ? dW2 : sW2;
      U[W2OFF_ + head * 32768 + idx] = f2b(src[o * 128 + k]);
    }
  }
}

// ---------------------------------------------------------------------------
// k_main: 1792 blocks = 256 stripes x 7; g=id%7, j=id/7.
//   g=0: MLP 4 molecules (j: which=j&1, mbase=(j>>1)*4)
//   g=1,2: bonds m=j*2+(g-1)
//   g=3,4: vdW+variance+linear m=j*2+(g-3)
//   g=5,6: x-write m=j*2+(g-5)
// ---------------------------------------------------------------------------
__global__ __launch_bounds__(256, 4) void k_main(
    const int* __restrict__ atom_types, const float* __restrict__ pos,
    const int* __restrict__ bonds, const float* __restrict__ emb,
    const float* __restrict__ bb, const float* __restrict__ sb1,
    const float* __restrict__ sb2, const float* __restrict__ sW3,
    const float* __restrict__ sb3, const float* __restrict__ db1,
    const float* __restrict__ db2, const float* __restrict__ dW3,
    const float* __restrict__ db3, const float* __restrict__ ws,
    float* __restrict__ out) {
  int id = blockIdx.x;
  int j = id / 7;
  int g = id - j * 7;
  int tid = threadIdx.x;
  const ushort* U = (const ushort*)(ws + U16BASE_);
  __shared__ float smem[3216];
  volatile float* red4 = smem + 3208;

  if (g == 0) {
    // ================= MLP: 4 molecules =================
    int which = j & 1;
    int mbase = (j >> 1) * 4;
    unsigned char* tyb = (unsigned char*)(smem + 3072);  // 512 B
    float* part = smem;       // [4][2][256] = 2048
    float* h1 = smem + 2048;  // [4][256] = 1024
    float* h2 = smem + 1024;  // [4][128] = 512 (reuses part after scratch)

    for (int u = tid; u < 4 * NN_; u += 256)
      tyb[u] = (unsigned char)atom_types[(size_t)mbase * NN_ + u];
    __syncthreads();

    // ---- layer 1 phase A: thread = (mi, half-of-atoms, o-octet), 8-wide
    {
      int mi = tid >> 6;
      int half = (tid >> 5) & 1;
      int ot = tid & 31;
      const ushort* Tb = U + (which ? TDOFF_ : 0) + ot * 8;
      const unsigned char* ty = tyb + mi * NN_ + half * 64;
      float a[8] = {0.f, 0.f, 0.f, 0.f, 0.f, 0.f, 0.f, 0.f};
      for (int n0 = 0; n0 < 64; n0 += 8) {
        u16x8 v[8];
#pragma unroll
        for (int u = 0; u < 8; ++u) {
          int n = half * 64 + n0 + u;
          v[u] = *(const u16x8*)(Tb + (((n * 6) + (int)ty[n0 + u]) << 8));
        }
#pragma unroll
        for (int u = 0; u < 8; ++u) {
#pragma unroll
          for (int jj = 0; jj < 8; ++jj) a[jj] += b2f(v[u][jj]);
        }
      }
      float* pp = part + mi * 512 + half * 256 + ot * 8;
#pragma unroll
      for (int jj = 0; jj < 8; ++jj) pp[jj] = a[jj];
    }
    __syncthreads();
    // ---- phase B: combine halves + bias + relu
    {
      float b1v = (which ? db1 : sb1)[tid];
#pragma unroll
      for (int mm = 0; mm < 4; ++mm)
        h1[mm * 256 + tid] =
            fmaxf(part[mm * 512 + tid] + part[mm * 512 + 256 + tid] + b1v, 0.f);
    }
    __syncthreads();

    // ---- layer 2: thread = (k, o-half); W2T row contiguous u16x8 loads
    {
      int k = tid & 127;
      int kh = tid >> 7;
      const ushort* Wp = U + W2OFF_ + which * 32768 + k * 256 + kh * 128;
      float acc[4] = {0.f, 0.f, 0.f, 0.f};
      for (int o0 = 0; o0 < 128; o0 += 16) {
        u16x8 wa = *(const u16x8*)(Wp + o0);
        u16x8 wb = *(const u16x8*)(Wp + o0 + 8);
        float wf[16];
#pragma unroll
        for (int u = 0; u < 8; ++u) {
          wf[u] = b2f(wa[u]);
          wf[u + 8] = b2f(wb[u]);
        }
#pragma unroll
        for (int mm = 0; mm < 4; ++mm) {
          const float* hp = h1 + mm * 256 + kh * 128 + o0;
          float s = 0.f;
#pragma unroll
          for (int u = 0; u < 16; ++u) s += hp[u] * wf[u];
          acc[mm] += s;
        }
      }
      __syncthreads();  // part reads done; reuse as scratch
      float* scr = part;  // [2][4][128] = 1024
#pragma unroll
      for (int mm = 0; mm < 4; ++mm) scr[kh * 512 + mm * 128 + k] = acc[mm];
      __syncthreads();
      if (tid < 128) {
        float b2v = (which ? db2 : sb2)[tid];
#pragma unroll
        for (int mm = 0; mm < 4; ++mm)
          h2[mm * 128 + tid] = fmaxf(
              b2v + scr[mm * 128 + tid] + scr[512 + mm * 128 + tid], 0.f);
      }
      __syncthreads();
    }

    // ---- layer 3: 4 parallel 32-lane reductions
    {
      int mm = tid >> 5;
      int ln = tid & 31;
      if (mm < 4) {
        const float* W3 = which ? dW3 : sW3;
        float s = 0.f;
#pragma unroll
        for (int u = 0; u < 4; ++u) {
          int kk = ln + (u << 5);
          s += h2[mm * 128 + kk] * W3[kk];
        }
#pragma unroll
        for (int off = 16; off > 0; off >>= 1) s += __shfl_down(s, off, 32);
        if (ln == 0) {
          float b3 = (which ? db3 : sb3)[0];
          out[(2 + which) * BB_ + mbase + mm] = 1.f / (1.f + __expf(-(s + b3)));
        }
      }
    }
  } else if (g < 3) {
    // ================= bonds =================
    int m = j * 2 + (g - 1);
    float* pE = smem;                                   // 144
    float* bbv = smem + 144;                            // 4
    unsigned char* tyb = (unsigned char*)(smem + 160);  // 128 B

    if (tid < 32) {
      int4 t4 = ((const int4*)(atom_types + (size_t)m * NN_))[tid];
      uchar4 u4;
      u4.x = (unsigned char)t4.x;
      u4.y = (unsigned char)t4.y;
      u4.z = (unsigned char)t4.z;
      u4.w = (unsigned char)t4.w;
      ((uchar4*)tyb)[tid] = u4;
    }
    if (tid >= 64 && tid < 208) pE[tid - 64] = ws[WS_PAIRE + tid - 64];
    if (tid >= 224 && tid < 228) bbv[tid - 224] = bb[tid - 224];
    __syncthreads();

    const int4* b4 = (const int4*)(bonds + (size_t)m * NN_ * NN_);
    float bp = 0.f;
#pragma unroll 4
    for (int it = 0; it < 16; ++it) {
      int li = tid + (it << 8);
      int i = li >> 5;
      int c = li & 31;
      if (c * 4 + 3 > i) {
        int4 v = b4[li];
        int j0 = c << 2;
        int ti6 = tyb[i] * 6;
        if (j0 + 0 > i && v.x > 0)
          bp += pE[(v.x - 1) * 36 + ti6 + tyb[j0 + 0]] + bbv[v.x - 1];
        if (j0 + 1 > i && v.y > 0)
          bp += pE[(v.y - 1) * 36 + ti6 + tyb[j0 + 1]] + bbv[v.y - 1];
        if (j0 + 2 > i && v.z > 0)
          bp += pE[(v.z - 1) * 36 + ti6 + tyb[j0 + 2]] + bbv[v.z - 1];
        if (j0 + 3 > i && v.w > 0)
          bp += pE[(v.w - 1) * 36 + ti6 + tyb[j0 + 3]] + bbv[v.w - 1];
      }
    }
    float e = block_reduce256(bp, red4, tid);
    if (tid == 0) atomicAdd(&out[m], e);
  } else if (g < 5) {
    // ================= vdW + variance + linear =================
    int m = j * 2 + (g - 3);
    float4* p4 = (float4*)smem;  // 512 f
    float* aev = smem + 520;
    float* entv = smem + 528;
    float* redm = smem + 544;  // 32 f
    if (tid < 128) {
      const float* pm = pos + (size_t)m * NN_ * 3 + 3 * tid;
      p4[tid] = make_float4(pm[0], pm[1], pm[2], 0.f);
    }
    if (tid >= 128 && tid < 128 + NE_) aev[tid - 128] = ws[WS_AE + tid - 128];
    if (tid >= 160 && tid < 160 + NE_) entv[tid - 160] = ws[WS_ENT + tid - 160];
    __syncthreads();

    int i = tid >> 1;
    int half = tid & 1;
    float4 pi = p4[i];
    float vp = 0.f;
#pragma unroll 8
    for (int u = 0; u < 64; ++u) {
      int jj = (half << 6) + u;
      float4 pj = p4[jj];
      float dx = pi.x - pj.x;
      float dy = pi.y - pj.y;
      float dz = pi.z - pj.z;
      float d2 = dx * dx + dy * dy + dz * dz;
      if (jj > i && d2 > 0.f) {
        float rc = __builtin_amdgcn_rcpf(d2);
        float r6 = rc * rc * rc;
        vp += 0.4f * (r6 * r6 - r6);
      }
    }

    float x = 0.f, y = 0.f, z = 0.f, sq = 0.f, ae = 0.f, en = 0.f;
    if (tid < 128) {
      float4 p = p4[tid];
      x = p.x;
      y = p.y;
      z = p.z;
      sq = x * x + y * y + z * z;
      int t = atom_types[(size_t)m * NN_ + tid];
      ae = aev[t];
      en = entv[t];
    }
    // fused 7-value reduction: wave-shuffle + single barrier
    float vals[7] = {vp, x, y, z, sq, ae, en};
#pragma unroll
    for (int v = 0; v < 7; ++v) {
#pragma unroll
      for (int off = 32; off > 0; off >>= 1)
        vals[v] += __shfl_down(vals[v], off);
    }
    int wv = tid >> 6, ln = tid & 63;
    if (ln == 0) {
#pragma unroll
      for (int v = 0; v < 7; ++v) redm[wv * 8 + v] = vals[v];
    }
    __syncthreads();
    if (tid == 0) {
      float S[7];
#pragma unroll
      for (int v = 0; v < 7; ++v)
        S[v] = redm[v] + redm[8 + v] + redm[16 + v] + redm[24 + v];
      float var = (S[4] - (S[1] * S[1] + S[2] * S[2] + S[3] * S[3]) *
                              (1.f / NN_)) *
                  (1.f / (NN_ - 1));
      atomicAdd(&out[m], S[0] + S[5]);
      out[BB_ + m] = S[6] + logf(1.f + var);  // single writer
    }
  } else {
    // ================= x-write =================
    int m = j * 2 + (g - 5);
    float* e_s = smem;  // 384
    unsigned char* tyb = (unsigned char*)(smem + 384);
    for (int i = tid; i < NE_ * DD_; i += 256) e_s[i] = emb[i];
    if (tid < 32) {
      int4 t4 = ((const int4*)(atom_types + (size_t)m * NN_))[tid];
      uchar4 u4;
      u4.x = (unsigned char)t4.x;
      u4.y = (unsigned char)t4.y;
      u4.z = (unsigned char)t4.z;
      u4.w = (unsigned char)t4.w;
      ((uchar4*)tyb)[tid] = u4;
    }
    __syncthreads();
    float4* out4 = (float4*)(out + 2048 + (size_t)m * (NN_ * DD_));
#pragma unroll
    for (int u = 0; u < 8; ++u) {
      int li = tid + (u << 8);
      int n = li >> 4;
      int d0 = (li & 15) << 2;
      out4[li] = *(const float4*)&e_s[tyb[n] * DD_ + d0];
    }
  }
}

// ---------------------------------------------------------------------------
extern "C" void kernel_launch(void* const* d_in, const int* in_sizes, int n_in,
                              void* d_out, int out_size, void* d_ws,
                              size_t ws_size, hipStream_t stream) {
  const int* atom_types = (const int*)d_in[0];
  const float* positions = (const float*)d_in[1];
  const int* bonds = (const int*)d_in[2];
  const float* emb = (const float*)d_in[3];
  const float* ae_w = (const float*)d_in[4];
  const float* ae_b = (const float*)d_in[5];
  const float* ent_w = (const float*)d_in[6];
  const float* ent_b = (const float*)d_in[7];
  const float* bW = (const float*)d_in[8];
  const float* bb = (const float*)d_in[9];
  const float* sW1 = (const float*)d_in[10];
  const float* sb1 = (const float*)d_in[11];
  const float* sW2 = (const float*)d_in[12];
  const float* sb2 = (const float*)d_in[13];
  const float* sW3 = (const float*)d_in[14];
  const float* sb3 = (const float*)d_in[15];
  const float* dW1 = (const float*)d_in[16];
  const float* db1 = (const float*)d_in[17];
  const float* dW2 = (const float*)d_in[18];
  const float* db2 = (const float*)d_in[19];
  const float* dW3 = (const float*)d_in[20];
  const float* db3 = (const float*)d_in[21];
  float* out = (float*)d_out;
  float* ws = (float*)d_ws;

  hipLaunchKernelGGL(k_pre, dim3(1186), dim3(256), 0, stream, emb, ae_w, ae_b,
                     ent_w, ent_b, bW, sW1, dW1, sW2, dW2, ws, out);
  hipLaunchKernelGGL(k_main, dim3(1792), dim3(256), 0, stream, atom_types,
                     positions, bonds, emb, bb, sb1, sb2, sW3, sb3, db1, db2,
                     dW3, db3, ws, out);
}

// Round 14
// 30.304 us; speedup vs baseline: 1.1243x; 1.1243x over previous
//
#include <hip/hip_runtime.h>
#include <math.h>

#define BB_ 512
#define NN_ 128
#define DD_ 64
#define NE_ 6
#define NB_ 4

// f32 workspace region (float offsets)
#define WS_PAIRE 0    // 144
#define WS_AE    144  // 6
#define WS_ENT   152  // 6
// ushort region at float offset 256:
//   [0, 768*256)        stability bf16 table, row (n*6+t)*256 + o
//   [TDOFF_, +768*256)  druglikeness bf16 table
//   [W2OFF_ + which*32768, +32768) W2 bf16 (o*128+k)
#define U16BASE_ 256
#define TDOFF_   (768 * 256)
#define W2OFF_   (1536 * 256)

typedef unsigned short u16x8 __attribute__((ext_vector_type(8)));
typedef int i32x4 __attribute__((ext_vector_type(4)));
typedef float f32x4 __attribute__((ext_vector_type(4)));

__device__ __forceinline__ ushort f2b(float f) {
  unsigned u = __float_as_uint(f);
  u += 0x7FFFu + ((u >> 16) & 1u);
  return (ushort)(u >> 16);
}
__device__ __forceinline__ float b2f(ushort h) {
  return __uint_as_float(((unsigned)h) << 16);
}

// ---------------------------------------------------------------------------
__device__ __forceinline__ float block_reduce256(float v, volatile float* red4,
                                                 int tid) {
#pragma unroll
  for (int off = 32; off > 0; off >>= 1) v += __shfl_down(v, off);
  __syncthreads();
  if ((tid & 63) == 0) red4[tid >> 6] = v;
  __syncthreads();
  return red4[0] + red4[1] + red4[2] + red4[3];
}

// ---------------------------------------------------------------------------
// k_pre: blk 0..511   -> bf16 layer1 tables (n=blk>>2, which=(blk>>1)&1, ohalf)
//        blk 512      -> zero out[0..1024)
//        blk 513..656 -> pairE entries
//        blk 657      -> ae/ent tables
//        blk 658..673 -> W2 bf16 conversion
// ---------------------------------------------------------------------------
__global__ __launch_bounds__(256, 4) void k_pre(
    const float* __restrict__ emb, const float* __restrict__ ae_w,
    const float* __restrict__ ae_b, const float* __restrict__ ent_w,
    const float* __restrict__ ent_b, const float* __restrict__ bW,
    const float* __restrict__ sW1, const float* __restrict__ dW1,
    const float* __restrict__ sW2, const float* __restrict__ dW2,
    float* __restrict__ ws, float* __restrict__ out) {
  int blk = blockIdx.x;
  int tid = threadIdx.x;
  ushort* U = (ushort*)(ws + U16BASE_);

  if (blk < 512) {
    int n = blk >> 2;
    int which = (blk >> 1) & 1;
    int ohalf = blk & 1;
    const float* W1 = which ? dW1 : sW1;
    ushort* T = U + (which ? TDOFF_ : 0);
    __shared__ float e_s[NE_ * DD_];
    __shared__ float part[NE_][128];
    for (int i = tid; i < NE_ * DD_; i += 256) e_s[i] = emb[i];
    __syncthreads();
    int o_local = tid & 127;
    int dhalf = tid >> 7;
    int o = ohalf * 128 + o_local;
    float acc[NE_] = {0.f, 0.f, 0.f, 0.f, 0.f, 0.f};
    const float* Wp = W1 + ((size_t)(n * DD_ + dhalf * 32)) * 256 + o;
#pragma unroll 8
    for (int d = 0; d < 32; ++d) {
      float w = __builtin_nontemporal_load(&Wp[(size_t)d * 256]);  // streamed once
#pragma unroll
      for (int t = 0; t < NE_; ++t) acc[t] += e_s[t * DD_ + dhalf * 32 + d] * w;
    }
    if (dhalf == 1) {
#pragma unroll
      for (int t = 0; t < NE_; ++t) part[t][o_local] = acc[t];
    }
    __syncthreads();
    if (dhalf == 0) {
#pragma unroll
      for (int t = 0; t < NE_; ++t)
        T[(n * NE_ + t) * 256 + o] = f2b(acc[t] + part[t][o_local]);
    }
  } else if (blk == 512) {
    float4 z = make_float4(0.f, 0.f, 0.f, 0.f);
    ((float4*)out)[tid] = z;  // out[0..1024): energy+entropy accumulators
  } else if (blk < 657) {
    int e = blk - 513;
    int k = e / 36;
    int rem = e - k * 36;
    int ti = rem / 6, tj = rem - (rem / 6) * 6;
    int d = tid & 63;
    int qd = tid >> 6;
    const float* Wrow = bW + ((size_t)k * DD_ + d) * DD_ + qd * 16;
    const float* xj = emb + tj * DD_ + qd * 16;
    float a = 0.f;
#pragma unroll
    for (int u = 0; u < 16; ++u) a += Wrow[u] * xj[u];
    float c = emb[ti * DD_ + d] * a;
    __shared__ float red4[4];
    c = block_reduce256(c, red4, tid);
    if (tid == 0) ws[WS_PAIRE + e] = c;
  } else if (blk == 657) {
    int g = tid >> 6, lane = tid & 63;
    for (int idx = g; idx < 12; idx += 4) {
      int t = idx - (idx >= 6 ? 6 : 0);
      bool ent = idx >= 6;
      float c = emb[t * DD_ + lane] * (ent ? ent_w[lane] : ae_w[lane]);
#pragma unroll
      for (int off = 32; off > 0; off >>= 1) c += __shfl_down(c, off);
      if (lane == 0)
        ws[(ent ? WS_ENT : WS_AE) + t] = c + (ent ? ent_b[0] : ae_b[0]);
    }
  } else {
    // W2 bf16 conversion: 16 blocks x 256 thr x 16 elems = 65536
    int base = (blk - 658) * 4096 + tid;
#pragma unroll
    for (int u = 0; u < 16; ++u) {
      int e = base + u * 256;
      int head = e >> 15;
      int idx = e & 32767;
      const float* src = head ? dW2 : sW2;
      U[W2OFF_ + e] = f2b(src[idx]);
    }
  }
}

// ---------------------------------------------------------------------------
// k_main: 1792 blocks (class-major).
//   [0,256)     : MLP, 4 molecules/block (which=id&1, grp=id>>1)
//   [256,768)   : bonds (nt loads)
//   [768,1280)  : vdW + variance + linear (fused single-barrier reduce)
//   [1280,1792) : x-write (nt stores)
// ---------------------------------------------------------------------------
__global__ __launch_bounds__(256, 4) void k_main(
    const int* __restrict__ atom_types, const float* __restrict__ pos,
    const int* __restrict__ bonds, const float* __restrict__ emb,
    const float* __restrict__ bb, const float* __restrict__ sb1,
    const float* __restrict__ sb2, const float* __restrict__ sW3,
    const float* __restrict__ sb3, const float* __restrict__ db1,
    const float* __restrict__ db2, const float* __restrict__ dW3,
    const float* __restrict__ db3, const float* __restrict__ ws,
    float* __restrict__ out) {
  int id = blockIdx.x;
  int tid = threadIdx.x;
  const ushort* U = (const ushort*)(ws + U16BASE_);
  __shared__ float smem[3216];
  volatile float* red4 = smem + 3208;

  if (id < 256) {
    // ================= MLP: 4 molecules =================
    int which = id & 1;
    int mbase = (id >> 1) * 4;
    unsigned char* tyb = (unsigned char*)(smem + 3072);  // 512 B
    float* part = smem;       // [4][2][256] = 2048
    float* h1 = smem + 2048;  // [4][256] = 1024
    float* h2 = smem + 1024;  // [4][128] = 512 (reuses part after scratch)

    for (int u = tid; u < 4 * NN_; u += 256)
      tyb[u] = (unsigned char)atom_types[(size_t)mbase * NN_ + u];
    __syncthreads();

    // ---- layer 1 phase A: thread = (mi, half-of-atoms, o-octet)
    {
      int mi = tid >> 6;
      int half = (tid >> 5) & 1;
      int ot = tid & 31;
      const ushort* Tb = U + (which ? TDOFF_ : 0) + ot * 8;
      const unsigned char* ty = tyb + mi * NN_ + half * 64;
      float a[8] = {0.f, 0.f, 0.f, 0.f, 0.f, 0.f, 0.f, 0.f};
      for (int n0 = 0; n0 < 64; n0 += 8) {
        u16x8 v[8];
#pragma unroll
        for (int u = 0; u < 8; ++u) {
          int n = half * 64 + n0 + u;
          v[u] = *(const u16x8*)(Tb + (((n * 6) + (int)ty[n0 + u]) << 8));
        }
#pragma unroll
        for (int u = 0; u < 8; ++u) {
#pragma unroll
          for (int j = 0; j < 8; ++j) a[j] += b2f(v[u][j]);
        }
      }
      float* pp = part + mi * 512 + half * 256 + ot * 8;
#pragma unroll
      for (int j = 0; j < 8; ++j) pp[j] = a[j];
    }
    __syncthreads();
    // ---- phase B: combine halves + bias + relu
    {
      float b1v = (which ? db1 : sb1)[tid];
#pragma unroll
      for (int mm = 0; mm < 4; ++mm)
        h1[mm * 256 + tid] =
            fmaxf(part[mm * 512 + tid] + part[mm * 512 + 256 + tid] + b1v, 0.f);
    }
    __syncthreads();

    // ---- layer 2: thread = (k, o-half); bf16 W2 regs reused over 4 mols
    {
      int k = tid & 127;
      int kh = tid >> 7;
      const ushort* Wp = U + W2OFF_ + which * 32768 + kh * 128 * 128 + k;
      float acc[4] = {0.f, 0.f, 0.f, 0.f};
      for (int o0 = 0; o0 < 128; o0 += 16) {
        float wf[16];
#pragma unroll
        for (int u = 0; u < 16; ++u) wf[u] = b2f(Wp[(o0 + u) << 7]);
#pragma unroll
        for (int mm = 0; mm < 4; ++mm) {
          const float* hp = h1 + mm * 256 + kh * 128 + o0;
          float s = 0.f;
#pragma unroll
          for (int u = 0; u < 16; ++u) s += hp[u] * wf[u];
          acc[mm] += s;
        }
      }
      __syncthreads();  // part reads done; reuse as scratch
      float* scr = part;  // [2][4][128] = 1024
#pragma unroll
      for (int mm = 0; mm < 4; ++mm) scr[kh * 512 + mm * 128 + k] = acc[mm];
      __syncthreads();
      if (tid < 128) {
        float b2v = (which ? db2 : sb2)[tid];
#pragma unroll
        for (int mm = 0; mm < 4; ++mm)
          h2[mm * 128 + tid] = fmaxf(
              b2v + scr[mm * 128 + tid] + scr[512 + mm * 128 + tid], 0.f);
      }
      __syncthreads();
    }

    // ---- layer 3: 4 parallel 32-lane reductions
    {
      int mm = tid >> 5;
      int ln = tid & 31;
      if (mm < 4) {
        const float* W3 = which ? dW3 : sW3;
        float s = 0.f;
#pragma unroll
        for (int u = 0; u < 4; ++u) {
          int kk = ln + (u << 5);
          s += h2[mm * 128 + kk] * W3[kk];
        }
#pragma unroll
        for (int off = 16; off > 0; off >>= 1) s += __shfl_down(s, off, 32);
        if (ln == 0) {
          float b3 = (which ? db3 : sb3)[0];
          out[(2 + which) * BB_ + mbase + mm] = 1.f / (1.f + __expf(-(s + b3)));
        }
      }
    }
  } else if (id < 768) {
    // ================= bonds =================
    int m = id - 256;
    float* pE = smem;                                   // 144
    float* bbv = smem + 144;                            // 4
    unsigned char* tyb = (unsigned char*)(smem + 160);  // 128 B

    if (tid < 32) {
      int4 t4 = ((const int4*)(atom_types + (size_t)m * NN_))[tid];
      uchar4 u4;
      u4.x = (unsigned char)t4.x;
      u4.y = (unsigned char)t4.y;
      u4.z = (unsigned char)t4.z;
      u4.w = (unsigned char)t4.w;
      ((uchar4*)tyb)[tid] = u4;
    }
    if (tid >= 64 && tid < 208) pE[tid - 64] = ws[WS_PAIRE + tid - 64];
    if (tid >= 224 && tid < 228) bbv[tid - 224] = bb[tid - 224];
    __syncthreads();

    const i32x4* b4 = (const i32x4*)(bonds + (size_t)m * NN_ * NN_);
    float bp = 0.f;
#pragma unroll 4
    for (int it = 0; it < 16; ++it) {
      int li = tid + (it << 8);
      int i = li >> 5;
      int c = li & 31;
      if (c * 4 + 3 > i) {
        i32x4 v = __builtin_nontemporal_load(&b4[li]);  // read-once stream
        int j0 = c << 2;
        int ti6 = tyb[i] * 6;
        if (j0 + 0 > i && v[0] > 0)
          bp += pE[(v[0] - 1) * 36 + ti6 + tyb[j0 + 0]] + bbv[v[0] - 1];
        if (j0 + 1 > i && v[1] > 0)
          bp += pE[(v[1] - 1) * 36 + ti6 + tyb[j0 + 1]] + bbv[v[1] - 1];
        if (j0 + 2 > i && v[2] > 0)
          bp += pE[(v[2] - 1) * 36 + ti6 + tyb[j0 + 2]] + bbv[v[2] - 1];
        if (j0 + 3 > i && v[3] > 0)
          bp += pE[(v[3] - 1) * 36 + ti6 + tyb[j0 + 3]] + bbv[v[3] - 1];
      }
    }
    float e = block_reduce256(bp, red4, tid);
    if (tid == 0) atomicAdd(&out[m], e);
  } else if (id < 1280) {
    // ================= vdW + variance + linear =================
    int m = id - 768;
    float4* p4 = (float4*)smem;  // 512 f
    float* aev = smem + 520;
    float* entv = smem + 528;
    float* redm = smem + 544;  // 32 f
    if (tid < 128) {
      const float* pm = pos + (size_t)m * NN_ * 3 + 3 * tid;
      p4[tid] = make_float4(pm[0], pm[1], pm[2], 0.f);
    }
    if (tid >= 128 && tid < 128 + NE_) aev[tid - 128] = ws[WS_AE + tid - 128];
    if (tid >= 160 && tid < 160 + NE_) entv[tid - 160] = ws[WS_ENT + tid - 160];
    __syncthreads();

    int i = tid >> 1;
    int half = tid & 1;
    float4 pi = p4[i];
    float vp = 0.f;
#pragma unroll 8
    for (int u = 0; u < 64; ++u) {
      int j = (half << 6) + u;
      float4 pj = p4[j];
      float dx = pi.x - pj.x;
      float dy = pi.y - pj.y;
      float dz = pi.z - pj.z;
      float d2 = dx * dx + dy * dy + dz * dz;
      if (j > i && d2 > 0.f) {
        float rc = __builtin_amdgcn_rcpf(d2);
        float r6 = rc * rc * rc;
        vp += 0.4f * (r6 * r6 - r6);
      }
    }

    float x = 0.f, y = 0.f, z = 0.f, sq = 0.f, ae = 0.f, en = 0.f;
    if (tid < 128) {
      float4 p = p4[tid];
      x = p.x;
      y = p.y;
      z = p.z;
      sq = x * x + y * y + z * z;
      int t = atom_types[(size_t)m * NN_ + tid];
      ae = aev[t];
      en = entv[t];
    }
    // fused 7-value reduction: wave-shuffle + single barrier
    float vals[7] = {vp, x, y, z, sq, ae, en};
#pragma unroll
    for (int v = 0; v < 7; ++v) {
#pragma unroll
      for (int off = 32; off > 0; off >>= 1)
        vals[v] += __shfl_down(vals[v], off);
    }
    int wv = tid >> 6, ln = tid & 63;
    if (ln == 0) {
#pragma unroll
      for (int v = 0; v < 7; ++v) redm[wv * 8 + v] = vals[v];
    }
    __syncthreads();
    if (tid == 0) {
      float S[7];
#pragma unroll
      for (int v = 0; v < 7; ++v)
        S[v] = redm[v] + redm[8 + v] + redm[16 + v] + redm[24 + v];
      float var = (S[4] - (S[1] * S[1] + S[2] * S[2] + S[3] * S[3]) *
                              (1.f / NN_)) *
                  (1.f / (NN_ - 1));
      atomicAdd(&out[m], S[0] + S[5]);
      out[BB_ + m] = S[6] + logf(1.f + var);  // single writer
    }
  } else {
    // ================= x-write =================
    int m = id - 1280;
    float* e_s = smem;  // 384
    unsigned char* tyb = (unsigned char*)(smem + 384);
    for (int i = tid; i < NE_ * DD_; i += 256) e_s[i] = emb[i];
    if (tid < 32) {
      int4 t4 = ((const int4*)(atom_types + (size_t)m * NN_))[tid];
      uchar4 u4;
      u4.x = (unsigned char)t4.x;
      u4.y = (unsigned char)t4.y;
      u4.z = (unsigned char)t4.z;
      u4.w = (unsigned char)t4.w;
      ((uchar4*)tyb)[tid] = u4;
    }
    __syncthreads();
    f32x4* out4 = (f32x4*)(out + 2048 + (size_t)m * (NN_ * DD_));
#pragma unroll
    for (int u = 0; u < 8; ++u) {
      int li = tid + (u << 8);
      int n = li >> 4;
      int d0 = (li & 15) << 2;
      f32x4 val = *(const f32x4*)&e_s[tyb[n] * DD_ + d0];
      __builtin_nontemporal_store(val, &out4[li]);  // never re-read
    }
  }
}

// ---------------------------------------------------------------------------
extern "C" void kernel_launch(void* const* d_in, const int* in_sizes, int n_in,
                              void* d_out, int out_size, void* d_ws,
                              size_t ws_size, hipStream_t stream) {
  const int* atom_types = (const int*)d_in[0];
  const float* positions = (const float*)d_in[1];
  const int* bonds = (const int*)d_in[2];
  const float* emb = (const float*)d_in[3];
  const float* ae_w = (const float*)d_in[4];
  const float* ae_b = (const float*)d_in[5];
  const float* ent_w = (const float*)d_in[6];
  const float* ent_b = (const float*)d_in[7];
  const float* bW = (const float*)d_in[8];
  const float* bb = (const float*)d_in[9];
  const float* sW1 = (const float*)d_in[10];
  const float* sb1 = (const float*)d_in[11];
  const float* sW2 = (const float*)d_in[12];
  const float* sb2 = (const float*)d_in[13];
  const float* sW3 = (const float*)d_in[14];
  const float* sb3 = (const float*)d_in[15];
  const float* dW1 = (const float*)d_in[16];
  const float* db1 = (const float*)d_in[17];
  const float* dW2 = (const float*)d_in[18];
  const float* db2 = (const float*)d_in[19];
  const float* dW3 = (const float*)d_in[20];
  const float* db3 = (const float*)d_in[21];
  float* out = (float*)d_out;
  float* ws = (float*)d_ws;

  hipLaunchKernelGGL(k_pre, dim3(674), dim3(256), 0, stream, emb, ae_w, ae_b,
                     ent_w, ent_b, bW, sW1, dW1, sW2, dW2, ws, out);
  hipLaunchKernelGGL(k_main, dim3(1792), dim3(256), 0, stream, atom_types,
                     positions, bonds, emb, bb, sb1, sb2, sW3, sb3, db1, db2,
                     dW3, db3, ws, out);
}

// Round 15
// 27.841 us; speedup vs baseline: 1.2238x; 1.0885x over previous
//
#include <hip/hip_runtime.h>
#include <math.h>

#define BB_ 512
#define NN_ 128
#define DD_ 64
#define NE_ 6
#define NB_ 4

// f32 workspace region (float offsets)
#define WS_PAIRE 0    // 144
#define WS_AE    144  // 6
#define WS_ENT   152  // 6
// ushort region at float offset 256:
//   [0, 768*256)        stability bf16 table, row (n*6+t)*256 + o
//   [TDOFF_, +768*256)  druglikeness bf16 table
//   [W2OFF_ + which*32768, +32768) W2 bf16 (o*128+k)
#define U16BASE_ 256
#define TDOFF_   (768 * 256)
#define W2OFF_   (1536 * 256)

typedef unsigned short u16x8 __attribute__((ext_vector_type(8)));

__device__ __forceinline__ ushort f2b(float f) {
  unsigned u = __float_as_uint(f);
  u += 0x7FFFu + ((u >> 16) & 1u);
  return (ushort)(u >> 16);
}
__device__ __forceinline__ float b2f(ushort h) {
  return __uint_as_float(((unsigned)h) << 16);
}

// ---------------------------------------------------------------------------
__device__ __forceinline__ float block_reduce256(float v, volatile float* red4,
                                                 int tid) {
#pragma unroll
  for (int off = 32; off > 0; off >>= 1) v += __shfl_down(v, off);
  __syncthreads();
  if ((tid & 63) == 0) red4[tid >> 6] = v;
  __syncthreads();
  return red4[0] + red4[1] + red4[2] + red4[3];
}

// ---------------------------------------------------------------------------
// k_pre: blk 0..511   -> bf16 layer1 tables (n=blk>>2, which=(blk>>1)&1, ohalf)
//        blk 512      -> zero out[0..1024)
//        blk 513..656 -> pairE entries
//        blk 657      -> ae/ent tables
//        blk 658..673 -> W2 bf16 conversion
// ---------------------------------------------------------------------------
__global__ __launch_bounds__(256, 4) void k_pre(
    const float* __restrict__ emb, const float* __restrict__ ae_w,
    const float* __restrict__ ae_b, const float* __restrict__ ent_w,
    const float* __restrict__ ent_b, const float* __restrict__ bW,
    const float* __restrict__ sW1, const float* __restrict__ dW1,
    const float* __restrict__ sW2, const float* __restrict__ dW2,
    float* __restrict__ ws, float* __restrict__ out) {
  int blk = blockIdx.x;
  int tid = threadIdx.x;
  ushort* U = (ushort*)(ws + U16BASE_);

  if (blk < 512) {
    int n = blk >> 2;
    int which = (blk >> 1) & 1;
    int ohalf = blk & 1;
    const float* W1 = which ? dW1 : sW1;
    ushort* T = U + (which ? TDOFF_ : 0);
    __shared__ float e_s[NE_ * DD_];
    __shared__ float part[NE_][128];
    for (int i = tid; i < NE_ * DD_; i += 256) e_s[i] = emb[i];
    __syncthreads();
    int o_local = tid & 127;
    int dhalf = tid >> 7;
    int o = ohalf * 128 + o_local;
    float acc[NE_] = {0.f, 0.f, 0.f, 0.f, 0.f, 0.f};
    const float* Wp = W1 + ((size_t)(n * DD_ + dhalf * 32)) * 256 + o;
#pragma unroll 8
    for (int d = 0; d < 32; ++d) {
      float w = Wp[(size_t)d * 256];
#pragma unroll
      for (int t = 0; t < NE_; ++t) acc[t] += e_s[t * DD_ + dhalf * 32 + d] * w;
    }
    if (dhalf == 1) {
#pragma unroll
      for (int t = 0; t < NE_; ++t) part[t][o_local] = acc[t];
    }
    __syncthreads();
    if (dhalf == 0) {
#pragma unroll
      for (int t = 0; t < NE_; ++t)
        T[(n * NE_ + t) * 256 + o] = f2b(acc[t] + part[t][o_local]);
    }
  } else if (blk == 512) {
    float4 z = make_float4(0.f, 0.f, 0.f, 0.f);
    ((float4*)out)[tid] = z;  // out[0..1024): energy+entropy accumulators
  } else if (blk < 657) {
    int e = blk - 513;
    int k = e / 36;
    int rem = e - k * 36;
    int ti = rem / 6, tj = rem - (rem / 6) * 6;
    int d = tid & 63;
    int qd = tid >> 6;
    const float* Wrow = bW + ((size_t)k * DD_ + d) * DD_ + qd * 16;
    const float* xj = emb + tj * DD_ + qd * 16;
    float a = 0.f;
#pragma unroll
    for (int u = 0; u < 16; ++u) a += Wrow[u] * xj[u];
    float c = emb[ti * DD_ + d] * a;
    __shared__ float red4[4];
    c = block_reduce256(c, red4, tid);
    if (tid == 0) ws[WS_PAIRE + e] = c;
  } else if (blk == 657) {
    int g = tid >> 6, lane = tid & 63;
    for (int idx = g; idx < 12; idx += 4) {
      int t = idx - (idx >= 6 ? 6 : 0);
      bool ent = idx >= 6;
      float c = emb[t * DD_ + lane] * (ent ? ent_w[lane] : ae_w[lane]);
#pragma unroll
      for (int off = 32; off > 0; off >>= 1) c += __shfl_down(c, off);
      if (lane == 0)
        ws[(ent ? WS_ENT : WS_AE) + t] = c + (ent ? ent_b[0] : ae_b[0]);
    }
  } else {
    // W2 bf16 conversion: 16 blocks x 256 thr x 16 elems = 65536
    int base = (blk - 658) * 4096 + tid;
#pragma unroll
    for (int u = 0; u < 16; ++u) {
      int e = base + u * 256;
      int head = e >> 15;
      int idx = e & 32767;
      const float* src = head ? dW2 : sW2;
      U[W2OFF_ + e] = f2b(src[idx]);
    }
  }
}

// ---------------------------------------------------------------------------
// k_main: 1792 blocks.
//   [0,256)     : MLP, 4 molecules/block (which=id&1, grp=id>>1)
//   [256,768)   : bonds
//   [768,1280)  : vdW + variance + linear (fused single-barrier reduce)
//   [1280,1792) : x-write
// ---------------------------------------------------------------------------
__global__ __launch_bounds__(256, 4) void k_main(
    const int* __restrict__ atom_types, const float* __restrict__ pos,
    const int* __restrict__ bonds, const float* __restrict__ emb,
    const float* __restrict__ bb, const float* __restrict__ sb1,
    const float* __restrict__ sb2, const float* __restrict__ sW3,
    const float* __restrict__ sb3, const float* __restrict__ db1,
    const float* __restrict__ db2, const float* __restrict__ dW3,
    const float* __restrict__ db3, const float* __restrict__ ws,
    float* __restrict__ out) {
  int id = blockIdx.x;
  int tid = threadIdx.x;
  const ushort* U = (const ushort*)(ws + U16BASE_);
  __shared__ float smem[3216];
  volatile float* red4 = smem + 3208;

  if (id < 256) {
    // ================= MLP: 4 molecules =================
    int which = id & 1;
    int mbase = (id >> 1) * 4;
    unsigned char* tyb = (unsigned char*)(smem + 3072);  // 512 B
    float* part = smem;       // [4][2][256] = 2048
    float* h1 = smem + 2048;  // [4][256] = 1024
    float* h2 = smem + 1024;  // [4][128] = 512 (reuses part after scratch)

    for (int u = tid; u < 4 * NN_; u += 256)
      tyb[u] = (unsigned char)atom_types[(size_t)mbase * NN_ + u];
    __syncthreads();

    // ---- layer 1 phase A: thread = (mi, half-of-atoms, o-octet)
    {
      int mi = tid >> 6;
      int half = (tid >> 5) & 1;
      int ot = tid & 31;
      const ushort* Tb = U + (which ? TDOFF_ : 0) + ot * 8;
      const unsigned char* ty = tyb + mi * NN_ + half * 64;
      float a[8] = {0.f, 0.f, 0.f, 0.f, 0.f, 0.f, 0.f, 0.f};
      for (int n0 = 0; n0 < 64; n0 += 8) {
        u16x8 v[8];
#pragma unroll
        for (int u = 0; u < 8; ++u) {
          int n = half * 64 + n0 + u;
          v[u] = *(const u16x8*)(Tb + (((n * 6) + (int)ty[n0 + u]) << 8));
        }
#pragma unroll
        for (int u = 0; u < 8; ++u) {
#pragma unroll
          for (int j = 0; j < 8; ++j) a[j] += b2f(v[u][j]);
        }
      }
      float* pp = part + mi * 512 + half * 256 + ot * 8;
#pragma unroll
      for (int j = 0; j < 8; ++j) pp[j] = a[j];
    }
    __syncthreads();
    // ---- phase B: combine halves + bias + relu
    {
      float b1v = (which ? db1 : sb1)[tid];
#pragma unroll
      for (int mm = 0; mm < 4; ++mm)
        h1[mm * 256 + tid] =
            fmaxf(part[mm * 512 + tid] + part[mm * 512 + 256 + tid] + b1v, 0.f);
    }
    __syncthreads();

    // ---- layer 2: thread = (k, o-half); bf16 W2 regs reused over 4 mols
    {
      int k = tid & 127;
      int kh = tid >> 7;
      const ushort* Wp = U + W2OFF_ + which * 32768 + kh * 128 * 128 + k;
      float acc[4] = {0.f, 0.f, 0.f, 0.f};
      for (int o0 = 0; o0 < 128; o0 += 16) {
        float wf[16];
#pragma unroll
        for (int u = 0; u < 16; ++u) wf[u] = b2f(Wp[(o0 + u) << 7]);
#pragma unroll
        for (int mm = 0; mm < 4; ++mm) {
          const float* hp = h1 + mm * 256 + kh * 128 + o0;
          float s = 0.f;
#pragma unroll
          for (int u = 0; u < 16; ++u) s += hp[u] * wf[u];
          acc[mm] += s;
        }
      }
      __syncthreads();  // part reads done; reuse as scratch
      float* scr = part;  // [2][4][128] = 1024
#pragma unroll
      for (int mm = 0; mm < 4; ++mm) scr[kh * 512 + mm * 128 + k] = acc[mm];
      __syncthreads();
      if (tid < 128) {
        float b2v = (which ? db2 : sb2)[tid];
#pragma unroll
        for (int mm = 0; mm < 4; ++mm)
          h2[mm * 128 + tid] = fmaxf(
              b2v + scr[mm * 128 + tid] + scr[512 + mm * 128 + tid], 0.f);
      }
      __syncthreads();
    }

    // ---- layer 3: 4 parallel 32-lane reductions
    {
      int mm = tid >> 5;
      int ln = tid & 31;
      if (mm < 4) {
        const float* W3 = which ? dW3 : sW3;
        float s = 0.f;
#pragma unroll
        for (int u = 0; u < 4; ++u) {
          int kk = ln + (u << 5);
          s += h2[mm * 128 + kk] * W3[kk];
        }
#pragma unroll
        for (int off = 16; off > 0; off >>= 1) s += __shfl_down(s, off, 32);
        if (ln == 0) {
          float b3 = (which ? db3 : sb3)[0];
          out[(2 + which) * BB_ + mbase + mm] = 1.f / (1.f + __expf(-(s + b3)));
        }
      }
    }
  } else if (id < 768) {
    // ================= bonds =================
    int m = id - 256;
    float* pE = smem;                                   // 144
    float* bbv = smem + 144;                            // 4
    unsigned char* tyb = (unsigned char*)(smem + 160);  // 128 B

    if (tid < 32) {
      int4 t4 = ((const int4*)(atom_types + (size_t)m * NN_))[tid];
      uchar4 u4;
      u4.x = (unsigned char)t4.x;
      u4.y = (unsigned char)t4.y;
      u4.z = (unsigned char)t4.z;
      u4.w = (unsigned char)t4.w;
      ((uchar4*)tyb)[tid] = u4;
    }
    if (tid >= 64 && tid < 208) pE[tid - 64] = ws[WS_PAIRE + tid - 64];
    if (tid >= 224 && tid < 228) bbv[tid - 224] = bb[tid - 224];
    __syncthreads();

    const int4* b4 = (const int4*)(bonds + (size_t)m * NN_ * NN_);
    float bp = 0.f;
#pragma unroll 4
    for (int it = 0; it < 16; ++it) {
      int li = tid + (it << 8);
      int i = li >> 5;
      int c = li & 31;
      if (c * 4 + 3 > i) {
        int4 v = b4[li];
        int j0 = c << 2;
        int ti6 = tyb[i] * 6;
        if (j0 + 0 > i && v.x > 0)
          bp += pE[(v.x - 1) * 36 + ti6 + tyb[j0 + 0]] + bbv[v.x - 1];
        if (j0 + 1 > i && v.y > 0)
          bp += pE[(v.y - 1) * 36 + ti6 + tyb[j0 + 1]] + bbv[v.y - 1];
        if (j0 + 2 > i && v.z > 0)
          bp += pE[(v.z - 1) * 36 + ti6 + tyb[j0 + 2]] + bbv[v.z - 1];
        if (j0 + 3 > i && v.w > 0)
          bp += pE[(v.w - 1) * 36 + ti6 + tyb[j0 + 3]] + bbv[v.w - 1];
      }
    }
    float e = block_reduce256(bp, red4, tid);
    if (tid == 0) atomicAdd(&out[m], e);
  } else if (id < 1280) {
    // ================= vdW + variance + linear =================
    int m = id - 768;
    float4* p4 = (float4*)smem;  // 512 f
    float* aev = smem + 520;
    float* entv = smem + 528;
    float* redm = smem + 544;  // 32 f
    if (tid < 128) {
      const float* pm = pos + (size_t)m * NN_ * 3 + 3 * tid;
      p4[tid] = make_float4(pm[0], pm[1], pm[2], 0.f);
    }
    if (tid >= 128 && tid < 128 + NE_) aev[tid - 128] = ws[WS_AE + tid - 128];
    if (tid >= 160 && tid < 160 + NE_) entv[tid - 160] = ws[WS_ENT + tid - 160];
    __syncthreads();

    int i = tid >> 1;
    int half = tid & 1;
    float4 pi = p4[i];
    float vp = 0.f;
#pragma unroll 8
    for (int u = 0; u < 64; ++u) {
      int j = (half << 6) + u;
      float4 pj = p4[j];
      float dx = pi.x - pj.x;
      float dy = pi.y - pj.y;
      float dz = pi.z - pj.z;
      float d2 = dx * dx + dy * dy + dz * dz;
      if (j > i && d2 > 0.f) {
        float rc = __builtin_amdgcn_rcpf(d2);
        float r6 = rc * rc * rc;
        vp += 0.4f * (r6 * r6 - r6);
      }
    }

    float x = 0.f, y = 0.f, z = 0.f, sq = 0.f, ae = 0.f, en = 0.f;
    if (tid < 128) {
      float4 p = p4[tid];
      x = p.x;
      y = p.y;
      z = p.z;
      sq = x * x + y * y + z * z;
      int t = atom_types[(size_t)m * NN_ + tid];
      ae = aev[t];
      en = entv[t];
    }
    // fused 7-value reduction: wave-shuffle + single barrier
    float vals[7] = {vp, x, y, z, sq, ae, en};
#pragma unroll
    for (int v = 0; v < 7; ++v) {
#pragma unroll
      for (int off = 32; off > 0; off >>= 1)
        vals[v] += __shfl_down(vals[v], off);
    }
    int wv = tid >> 6, ln = tid & 63;
    if (ln == 0) {
#pragma unroll
      for (int v = 0; v < 7; ++v) redm[wv * 8 + v] = vals[v];
    }
    __syncthreads();
    if (tid == 0) {
      float S[7];
#pragma unroll
      for (int v = 0; v < 7; ++v)
        S[v] = redm[v] + redm[8 + v] + redm[16 + v] + redm[24 + v];
      float var = (S[4] - (S[1] * S[1] + S[2] * S[2] + S[3] * S[3]) *
                              (1.f / NN_)) *
                  (1.f / (NN_ - 1));
      atomicAdd(&out[m], S[0] + S[5]);
      out[BB_ + m] = S[6] + logf(1.f + var);  // single writer
    }
  } else {
    // ================= x-write =================
    int m = id - 1280;
    float* e_s = smem;  // 384
    unsigned char* tyb = (unsigned char*)(smem + 384);
    for (int i = tid; i < NE_ * DD_; i += 256) e_s[i] = emb[i];
    if (tid < 32) {
      int4 t4 = ((const int4*)(atom_types + (size_t)m * NN_))[tid];
      uchar4 u4;
      u4.x = (unsigned char)t4.x;
      u4.y = (unsigned char)t4.y;
      u4.z = (unsigned char)t4.z;
      u4.w = (unsigned char)t4.w;
      ((uchar4*)tyb)[tid] = u4;
    }
    __syncthreads();
    float4* out4 = (float4*)(out + 2048 + (size_t)m * (NN_ * DD_));
#pragma unroll
    for (int u = 0; u < 8; ++u) {
      int li = tid + (u << 8);
      int n = li >> 4;
      int d0 = (li & 15) << 2;
      out4[li] = *(const float4*)&e_s[tyb[n] * DD_ + d0];
    }
  }
}

// ---------------------------------------------------------------------------
extern "C" void kernel_launch(void* const* d_in, const int* in_sizes, int n_in,
                              void* d_out, int out_size, void* d_ws,
                              size_t ws_size, hipStream_t stream) {
  const int* atom_types = (const int*)d_in[0];
  const float* positions = (const float*)d_in[1];
  const int* bonds = (const int*)d_in[2];
  const float* emb = (const float*)d_in[3];
  const float* ae_w = (const float*)d_in[4];
  const float* ae_b = (const float*)d_in[5];
  const float* ent_w = (const float*)d_in[6];
  const float* ent_b = (const float*)d_in[7];
  const float* bW = (const float*)d_in[8];
  const float* bb = (const float*)d_in[9];
  const float* sW1 = (const float*)d_in[10];
  const float* sb1 = (const float*)d_in[11];
  const float* sW2 = (const float*)d_in[12];
  const float* sb2 = (const float*)d_in[13];
  const float* sW3 = (const float*)d_in[14];
  const float* sb3 = (const float*)d_in[15];
  const float* dW1 = (const float*)d_in[16];
  const float* db1 = (const float*)d_in[17];
  const float* dW2 = (const float*)d_in[18];
  const float* db2 = (const float*)d_in[19];
  const float* dW3 = (const float*)d_in[20];
  const float* db3 = (const float*)d_in[21];
  float* out = (float*)d_out;
  float* ws = (float*)d_ws;

  hipLaunchKernelGGL(k_pre, dim3(674), dim3(256), 0, stream, emb, ae_w, ae_b,
                     ent_w, ent_b, bW, sW1, dW1, sW2, dW2, ws, out);
  hipLaunchKernelGGL(k_main, dim3(1792), dim3(256), 0, stream, atom_types,
                     positions, bonds, emb, bb, sb1, sb2, sW3, sb3, db1, db2,
                     dW3, db3, ws, out);
}